// Round 1
// baseline (931.510 us; speedup 1.0000x reference)
//
#include <hip/hip_runtime.h>

#define H 128

// deg[i] = 1 (self loop)
__global__ __launch_bounds__(256) void k_deg_init(float* deg, int N) {
  int i = blockIdx.x * 256 + threadIdx.x;
  if (i < N) deg[i] = 1.0f;
}

// deg[dst] += 1 per edge
__global__ __launch_bounds__(256) void k_deg_count(const int* __restrict__ dst, float* deg, int E) {
  int e = blockIdx.x * 256 + threadIdx.x;
  if (e < E) atomicAdd(&deg[dst[e]], 1.0f);
}

// deg -> rsqrt(deg)  (deg >= 1 always, self loops)
__global__ __launch_bounds__(256) void k_dinv(float* deg, int N) {
  int i = blockIdx.x * 256 + threadIdx.x;
  if (i < N) deg[i] = rsqrtf(deg[i]);
}

// h = x @ W^T.  Block handles 64 output cols (blockIdx&1) x node chunks of 8.
// W half staged transposed in LDS: Wl[k][o] so lanes (o consecutive) are conflict-free.
__global__ __launch_bounds__(256) void k_linear(const float* __restrict__ x, const float* __restrict__ W,
                                                float* __restrict__ h, int N) {
  __shared__ float Wl[128][64];   // 32 KiB: Wl[k][o] = W[(bo+o)*128+k]
  __shared__ float xs[8][128];    // 4 KiB
  const int bo   = (blockIdx.x & 1) * 64;
  const int o    = threadIdx.x & 63;
  const int slot = threadIdx.x >> 6;   // 0..3
  for (int i = threadIdx.x; i < 128 * 64; i += 256) {
    int k = i >> 6, oo = i & 63;
    Wl[k][oo] = W[(bo + oo) * 128 + k];
  }
  const int nstep = (gridDim.x >> 1) * 8;
  for (int n0 = (blockIdx.x >> 1) * 8; n0 < N; n0 += nstep) {
    __syncthreads();   // covers Wl on first iter, protects xs re-use afterwards
    for (int i = threadIdx.x; i < 8 * 128; i += 256) {
      int nn = n0 + (i >> 7);
      xs[i >> 7][i & 127] = (nn < N) ? x[(long)nn * H + (i & 127)] : 0.f;
    }
    __syncthreads();
    float a0 = 0.f, a1 = 0.f;
    const int r0 = slot * 2, r1 = slot * 2 + 1;
    #pragma unroll 8
    for (int k = 0; k < 128; ++k) {
      float w = Wl[k][o];
      a0 += xs[r0][k] * w;
      a1 += xs[r1][k] * w;
    }
    int na = n0 + r0, nb = n0 + r1;
    if (na < N) h[(long)na * H + bo + o] = a0;
    if (nb < N) h[(long)nb * H + bo + o] = a1;
  }
}

// out = h * dinv^2 (self loop message) + b   -- full overwrite of d_out, no atomics
__global__ __launch_bounds__(256) void k_self(const float* __restrict__ h, const float* __restrict__ dinv,
                                              const float* __restrict__ b, float* __restrict__ out, long total) {
  long idx = (long)blockIdx.x * 256 + threadIdx.x;
  if (idx < total) {
    int i = (int)(idx >> 7), c = (int)(idx & 127);
    float di = dinv[i];
    out[idx] = h[idx] * di * di + b[c];
  }
}

// per-edge: out[dst] += h[src] * dinv[src] * dinv[dst]   (2 messages per 256-thr block)
__global__ __launch_bounds__(256) void k_edges(const int* __restrict__ src, const int* __restrict__ dst,
                                               const float* __restrict__ h, const float* __restrict__ dinv,
                                               float* out, int E) {
  int m = blockIdx.x * 2 + (threadIdx.x >> 7);
  if (m >= E) return;
  int c = threadIdx.x & 127;
  int s = src[m], d = dst[m];
  float norm = dinv[s] * dinv[d];
  atomicAdd(&out[(long)d * H + c], h[(long)s * H + c] * norm);
}

extern "C" void kernel_launch(void* const* d_in, const int* in_sizes, int n_in,
                              void* d_out, int out_size, void* d_ws, size_t ws_size,
                              hipStream_t stream) {
  const float* x = (const float*)d_in[0];
  const int*   edge = (const int*)d_in[1];   // int64 inputs arrive as int32 per harness
  const float* W = (const float*)d_in[2];
  const float* b = (const float*)d_in[3];
  float* out = (float*)d_out;

  const int N = in_sizes[0] / H;     // 100000
  const int E = in_sizes[1] / 2;     // 1600000
  const int* src = edge;             // edge_index[0]
  const int* dst = edge + E;         // edge_index[1]

  float* deg = (float*)d_ws;         // N floats; becomes dinv in place
  float* h   = deg + N;              // N*H floats

  k_deg_init<<<(N + 255) / 256, 256, 0, stream>>>(deg, N);
  k_deg_count<<<(E + 255) / 256, 256, 0, stream>>>(dst, deg, E);
  k_dinv<<<(N + 255) / 256, 256, 0, stream>>>(deg, N);
  k_linear<<<2048, 256, 0, stream>>>(x, W, h, N);
  long total = (long)N * H;
  k_self<<<(int)((total + 255) / 256), 256, 0, stream>>>(h, deg, b, out, total);
  k_edges<<<(E + 1) / 2, 256, 0, stream>>>(src, dst, h, deg, out, E);
}

// Round 2
// 615.235 us; speedup vs baseline: 1.5141x; 1.5141x over previous
//
#include <hip/hip_runtime.h>

#define H 128
#define SCAN_BLK 1024   // elements per scan block (256 thr x 4)

// ---------------- degree / dinv ----------------
__global__ __launch_bounds__(256) void k_deg_count(const int* __restrict__ dst, int* deg, int E) {
  int e = blockIdx.x * 256 + threadIdx.x;
  if (e < E) atomicAdd(&deg[dst[e]], 1);
}

__global__ __launch_bounds__(256) void k_dinv(const int* __restrict__ deg, float* __restrict__ dinv, int N) {
  int i = blockIdx.x * 256 + threadIdx.x;
  if (i < N) dinv[i] = rsqrtf((float)(1 + deg[i]));   // +1 self loop
}

// ---------------- exclusive scan (3-pass) ----------------
__global__ __launch_bounds__(256) void k_scan1(const int* __restrict__ in, int* __restrict__ out,
                                               int* __restrict__ bsum, int N) {
  __shared__ int ls[256];
  const int base = blockIdx.x * SCAN_BLK + threadIdx.x * 4;
  int v0 = 0, v1 = 0, v2 = 0, v3 = 0;
  if (base + 3 < N) {
    const int4 q = *(const int4*)(in + base);
    v0 = q.x; v1 = q.y; v2 = q.z; v3 = q.w;
  } else {
    if (base     < N) v0 = in[base];
    if (base + 1 < N) v1 = in[base + 1];
    if (base + 2 < N) v2 = in[base + 2];
    if (base + 3 < N) v3 = in[base + 3];
  }
  const int t = v0 + v1 + v2 + v3;
  ls[threadIdx.x] = t;
  __syncthreads();
  for (int off = 1; off < 256; off <<= 1) {
    int x = (threadIdx.x >= off) ? ls[threadIdx.x - off] : 0;
    __syncthreads();
    ls[threadIdx.x] += x;
    __syncthreads();
  }
  const int excl = ls[threadIdx.x] - t;
  if (threadIdx.x == 255) bsum[blockIdx.x] = ls[255];
  const int e0 = excl, e1 = e0 + v0, e2 = e1 + v1, e3 = e2 + v2;
  if (base     < N) out[base]     = e0;
  if (base + 1 < N) out[base + 1] = e1;
  if (base + 2 < N) out[base + 2] = e2;
  if (base + 3 < N) out[base + 3] = e3;
}

__global__ __launch_bounds__(128) void k_scan2(int* bsum, int nb) {
  __shared__ int ls[128];
  int t = (threadIdx.x < nb) ? bsum[threadIdx.x] : 0;
  ls[threadIdx.x] = t;
  __syncthreads();
  for (int off = 1; off < 128; off <<= 1) {
    int x = (threadIdx.x >= off) ? ls[threadIdx.x - off] : 0;
    __syncthreads();
    ls[threadIdx.x] += x;
    __syncthreads();
  }
  if (threadIdx.x < nb) bsum[threadIdx.x] = ls[threadIdx.x] - t;  // exclusive
}

__global__ __launch_bounds__(256) void k_scan3(int* out, const int* __restrict__ bsum, int N, int E) {
  const int add = bsum[blockIdx.x];
  const int base = blockIdx.x * SCAN_BLK + threadIdx.x * 4;
  #pragma unroll
  for (int j = 0; j < 4; ++j) {
    int idx = base + j;
    if (idx < N) out[idx] += add;
  }
  if (blockIdx.x == 0 && threadIdx.x == 0) out[N] = E;
}

// ---------------- CSR fill ----------------
__global__ __launch_bounds__(256) void k_fill(const int* __restrict__ src, const int* __restrict__ dst,
                                              const int* __restrict__ row_off, int* cursor,
                                              int* __restrict__ csr_src, int E) {
  int e = blockIdx.x * 256 + threadIdx.x;
  if (e < E) {
    int d = dst[e];
    int p = atomicAdd(&cursor[d], 1);
    csr_src[row_off[d] + p] = src[e];
  }
}

// ---------------- linear: h = x @ W^T ----------------
__global__ __launch_bounds__(256) void k_linear(const float* __restrict__ x, const float* __restrict__ W,
                                                float* __restrict__ h, int N) {
  __shared__ float Wl[128][64];
  __shared__ float xs[8][128];
  const int bo   = (blockIdx.x & 1) * 64;
  const int o    = threadIdx.x & 63;
  const int slot = threadIdx.x >> 6;
  for (int i = threadIdx.x; i < 128 * 64; i += 256) {
    int k = i >> 6, oo = i & 63;
    Wl[k][oo] = W[(bo + oo) * 128 + k];
  }
  const int nstep = (gridDim.x >> 1) * 8;
  for (int n0 = (blockIdx.x >> 1) * 8; n0 < N; n0 += nstep) {
    __syncthreads();
    for (int i = threadIdx.x; i < 8 * 128; i += 256) {
      int nn = n0 + (i >> 7);
      xs[i >> 7][i & 127] = (nn < N) ? x[(long)nn * H + (i & 127)] : 0.f;
    }
    __syncthreads();
    float a0 = 0.f, a1 = 0.f;
    const int r0 = slot * 2, r1 = slot * 2 + 1;
    #pragma unroll 8
    for (int k = 0; k < 128; ++k) {
      float w = Wl[k][o];
      a0 += xs[r0][k] * w;
      a1 += xs[r1][k] * w;
    }
    int na = n0 + r0, nb = n0 + r1;
    if (na < N) h[(long)na * H + bo + o] = a0;
    if (nb < N) h[(long)nb * H + bo + o] = a1;
  }
}

// ---------------- aggregation: register accumulate per node ----------------
__global__ __launch_bounds__(256) void k_agg(const float* __restrict__ h, const float* __restrict__ dinv,
                                             const int* __restrict__ row_off, const int* __restrict__ csr_src,
                                             const float* __restrict__ b, float* __restrict__ out, int N) {
  const int d = blockIdx.x * 2 + (threadIdx.x >> 7);
  if (d >= N) return;
  const int c = threadIdx.x & 127;
  const float dd = dinv[d];
  float acc = h[d * H + c] * dd;            // self message (× dd again at end)
  const int beg = row_off[d], end = row_off[d + 1];
  for (int j = beg; j < end; ++j) {
    int s = csr_src[j];
    acc += h[s * H + c] * dinv[s];
  }
  out[d * H + c] = acc * dd + b[c];
}

// ---------------- fallback (atomic path) if ws too small ----------------
__global__ __launch_bounds__(256) void k_self(const float* __restrict__ h, const float* __restrict__ dinv,
                                              const float* __restrict__ b, float* __restrict__ out, long total) {
  long idx = (long)blockIdx.x * 256 + threadIdx.x;
  if (idx < total) {
    int i = (int)(idx >> 7), c = (int)(idx & 127);
    float di = dinv[i];
    out[idx] = h[idx] * di * di + b[c];
  }
}
__global__ __launch_bounds__(256) void k_edges(const int* __restrict__ src, const int* __restrict__ dst,
                                               const float* __restrict__ h, const float* __restrict__ dinv,
                                               float* out, int E) {
  int m = blockIdx.x * 2 + (threadIdx.x >> 7);
  if (m >= E) return;
  int c = threadIdx.x & 127;
  int s = src[m], d = dst[m];
  float norm = dinv[s] * dinv[d];
  atomicAdd(&out[(long)d * H + c], h[(long)s * H + c] * norm);
}

extern "C" void kernel_launch(void* const* d_in, const int* in_sizes, int n_in,
                              void* d_out, int out_size, void* d_ws, size_t ws_size,
                              hipStream_t stream) {
  const float* x = (const float*)d_in[0];
  const int*   edge = (const int*)d_in[1];
  const float* W = (const float*)d_in[2];
  const float* b = (const float*)d_in[3];
  float* out = (float*)d_out;

  const int N = in_sizes[0] / H;     // 100000
  const int E = in_sizes[1] / 2;     // 1600000
  const int* src = edge;
  const int* dst = edge + E;
  const int NB = (N + SCAN_BLK - 1) / SCAN_BLK;   // 98

  // workspace layout (all 4B elements)
  char* w = (char*)d_ws;
  float* h      = (float*)w;                 w += (size_t)N * H * 4;   // 51.2 MB
  float* dinv   = (float*)w;                 w += (size_t)N * 4;
  int*   deg    = (int*)w;                   w += (size_t)N * 4;
  int*   row_off= (int*)w;                   w += (size_t)(N + 1) * 4;
  int*   cursor = (int*)w;                   w += (size_t)N * 4;
  int*   bsum   = (int*)w;                   w += (size_t)256 * 4;
  int*   csr    = (int*)w;                   w += (size_t)E * 4;
  size_t need = (size_t)(w - (char*)d_ws);

  k_linear<<<2048, 256, 0, stream>>>(x, W, h, N);

  if (need <= ws_size) {
    hipMemsetAsync(deg, 0, (size_t)N * 4, stream);
    hipMemsetAsync(cursor, 0, (size_t)N * 4, stream);
    k_deg_count<<<(E + 255) / 256, 256, 0, stream>>>(dst, deg, E);
    k_dinv<<<(N + 255) / 256, 256, 0, stream>>>(deg, dinv, N);
    k_scan1<<<NB, 256, 0, stream>>>(deg, row_off, bsum, N);
    k_scan2<<<1, 128, 0, stream>>>(bsum, NB);
    k_scan3<<<NB, 256, 0, stream>>>(row_off, bsum, N, E);
    k_fill<<<(E + 255) / 256, 256, 0, stream>>>(src, dst, row_off, cursor, csr, E);
    k_agg<<<(N + 1) / 2, 256, 0, stream>>>(h, dinv, row_off, csr, b, out, N);
  } else {
    // fallback: atomic scatter path (round-1)
    float* degf = dinv;
    hipMemsetAsync(degf, 0, (size_t)N * 4, stream);
    k_deg_count<<<(E + 255) / 256, 256, 0, stream>>>(dst, (int*)degf, E);
    k_dinv<<<(N + 255) / 256, 256, 0, stream>>>((int*)degf, degf, N);
    long total = (long)N * H;
    k_self<<<(int)((total + 255) / 256), 256, 0, stream>>>(h, degf, b, out, total);
    k_edges<<<(E + 1) / 2, 256, 0, stream>>>(src, dst, h, degf, out, E);
  }
}

// Round 3
// 304.546 us; speedup vs baseline: 3.0587x; 2.0202x over previous
//
#include <hip/hip_runtime.h>

#define H 128
#define SCAN_BLK 1024

typedef __attribute__((ext_vector_type(8))) short short8_t;   // 8 bf16
typedef __attribute__((ext_vector_type(4))) float float4_t;

__device__ __forceinline__ ushort f2bf(float f) {
  uint u = __float_as_uint(f);
  u += 0x7fff + ((u >> 16) & 1);          // RNE
  return (ushort)(u >> 16);
}
__device__ __forceinline__ float bflo(uint v) { return __uint_as_float(v << 16); }
__device__ __forceinline__ float bfhi(uint v) { return __uint_as_float(v & 0xffff0000u); }

// ---------------- degree / dinv ----------------
__global__ __launch_bounds__(256) void k_deg_count(const int* __restrict__ dst, int* deg, int E) {
  int e = blockIdx.x * 256 + threadIdx.x;
  if (e < E) atomicAdd(&deg[dst[e]], 1);
}

__global__ __launch_bounds__(256) void k_dinv(const int* __restrict__ deg, float* __restrict__ dinv, int N) {
  int i = blockIdx.x * 256 + threadIdx.x;
  if (i < N) dinv[i] = rsqrtf((float)(1 + deg[i]));   // +1 self loop
}

// ---------------- exclusive scan (3-pass) ----------------
__global__ __launch_bounds__(256) void k_scan1(const int* __restrict__ in, int* __restrict__ out,
                                               int* __restrict__ bsum, int N) {
  __shared__ int ls[256];
  const int base = blockIdx.x * SCAN_BLK + threadIdx.x * 4;
  int v0 = 0, v1 = 0, v2 = 0, v3 = 0;
  if (base + 3 < N) {
    const int4 q = *(const int4*)(in + base);
    v0 = q.x; v1 = q.y; v2 = q.z; v3 = q.w;
  } else {
    if (base     < N) v0 = in[base];
    if (base + 1 < N) v1 = in[base + 1];
    if (base + 2 < N) v2 = in[base + 2];
    if (base + 3 < N) v3 = in[base + 3];
  }
  const int t = v0 + v1 + v2 + v3;
  ls[threadIdx.x] = t;
  __syncthreads();
  for (int off = 1; off < 256; off <<= 1) {
    int x = (threadIdx.x >= off) ? ls[threadIdx.x - off] : 0;
    __syncthreads();
    ls[threadIdx.x] += x;
    __syncthreads();
  }
  const int excl = ls[threadIdx.x] - t;
  if (threadIdx.x == 255) bsum[blockIdx.x] = ls[255];
  const int e0 = excl, e1 = e0 + v0, e2 = e1 + v1, e3 = e2 + v2;
  if (base     < N) out[base]     = e0;
  if (base + 1 < N) out[base + 1] = e1;
  if (base + 2 < N) out[base + 2] = e2;
  if (base + 3 < N) out[base + 3] = e3;
}

__global__ __launch_bounds__(128) void k_scan2(int* bsum, int nb) {
  __shared__ int ls[128];
  int t = (threadIdx.x < nb) ? bsum[threadIdx.x] : 0;
  ls[threadIdx.x] = t;
  __syncthreads();
  for (int off = 1; off < 128; off <<= 1) {
    int x = (threadIdx.x >= off) ? ls[threadIdx.x - off] : 0;
    __syncthreads();
    ls[threadIdx.x] += x;
    __syncthreads();
  }
  if (threadIdx.x < nb) bsum[threadIdx.x] = ls[threadIdx.x] - t;  // exclusive
}

__global__ __launch_bounds__(256) void k_scan3(int* out, const int* __restrict__ bsum, int N, int E) {
  const int add = bsum[blockIdx.x];
  const int base = blockIdx.x * SCAN_BLK + threadIdx.x * 4;
  #pragma unroll
  for (int j = 0; j < 4; ++j) {
    int idx = base + j;
    if (idx < N) out[idx] += add;
  }
  if (blockIdx.x == 0 && threadIdx.x == 0) out[N] = E;
}

// ---------------- CSR fill ----------------
__global__ __launch_bounds__(256) void k_fill(const int* __restrict__ src, const int* __restrict__ dst,
                                              const int* __restrict__ row_off, int* cursor,
                                              int* __restrict__ csr_src, int E) {
  int e = blockIdx.x * 256 + threadIdx.x;
  if (e < E) {
    int d = dst[e];
    int p = atomicAdd(&cursor[d], 1);
    csr_src[row_off[d] + p] = src[e];
  }
}

// ---------------- linear: hs = (x @ W^T) * dinv[row], stored bf16 ----------------
// Block: 256 thr = 4 waves. Tile 32 rows x 128 cols. Wave: rows rg*16.., cols cg*64..
// MFMA 16x16x32 bf16; W-fragments (B^T layout: W[out][in] rows read along K) in registers.
__global__ __launch_bounds__(256) void k_linear(const float* __restrict__ x, const float* __restrict__ W,
                                                const float* __restrict__ dinv, ushort* __restrict__ hs, int N) {
  __shared__ float CT[32 * 128];
  const int tid  = threadIdx.x;
  const int lane = tid & 63;
  const int wid  = tid >> 6;       // 0..3
  const int rg   = wid >> 1;       // row group 0..1
  const int cg   = wid & 1;        // col group 0..1
  const int q    = lane >> 4;      // quarter 0..3 -> k subgroup
  const int lm   = lane & 15;

  // B fragments: col = cg*64 + nf*16 + lm, k = kk*32 + q*8 + j (contiguous in W row)
  short8_t bfr[4][4];
  #pragma unroll
  for (int kk = 0; kk < 4; ++kk) {
    #pragma unroll
    for (int nf = 0; nf < 4; ++nf) {
      const float* wp = W + (cg * 64 + nf * 16 + lm) * 128 + kk * 32 + q * 8;
      float4_t w0 = *(const float4_t*)wp;
      float4_t w1 = *(const float4_t*)(wp + 4);
      union { short8_t s; ushort u[8]; } t;
      t.u[0] = f2bf(w0.x); t.u[1] = f2bf(w0.y); t.u[2] = f2bf(w0.z); t.u[3] = f2bf(w0.w);
      t.u[4] = f2bf(w1.x); t.u[5] = f2bf(w1.y); t.u[6] = f2bf(w1.z); t.u[7] = f2bf(w1.w);
      bfr[kk][nf] = t.s;
    }
  }

  const int ntiles = (N + 31) / 32;
  for (int tile = blockIdx.x; tile < ntiles; tile += gridDim.x) {
    const int n0 = tile * 32;
    const int arow = n0 + rg * 16 + lm;
    const int arow_c = (arow < N) ? arow : (N - 1);
    const float* xp = x + (long)arow_c * H + q * 8;
    short8_t afr[4];
    #pragma unroll
    for (int kk = 0; kk < 4; ++kk) {
      float4_t x0 = *(const float4_t*)(xp + kk * 32);
      float4_t x1 = *(const float4_t*)(xp + kk * 32 + 4);
      union { short8_t s; ushort u[8]; } t;
      t.u[0] = f2bf(x0.x); t.u[1] = f2bf(x0.y); t.u[2] = f2bf(x0.z); t.u[3] = f2bf(x0.w);
      t.u[4] = f2bf(x1.x); t.u[5] = f2bf(x1.y); t.u[6] = f2bf(x1.z); t.u[7] = f2bf(x1.w);
      afr[kk] = t.s;
    }

    float4_t acc[4];
    #pragma unroll
    for (int nf = 0; nf < 4; ++nf) acc[nf] = (float4_t){0.f, 0.f, 0.f, 0.f};
    #pragma unroll
    for (int kk = 0; kk < 4; ++kk) {
      #pragma unroll
      for (int nf = 0; nf < 4; ++nf)
        acc[nf] = __builtin_amdgcn_mfma_f32_16x16x32_bf16(afr[kk], bfr[kk][nf], acc[nf], 0, 0, 0);
    }

    // C/D layout: col = lane&15, row = (lane>>4)*4 + reg
    #pragma unroll
    for (int nf = 0; nf < 4; ++nf) {
      #pragma unroll
      for (int r = 0; r < 4; ++r)
        CT[(rg * 16 + q * 4 + r) * 128 + cg * 64 + nf * 16 + lm] = acc[nf][r];
    }
    __syncthreads();

    // coalesced: thread reads 16B contiguous LDS per round, scales, packs bf16
    #pragma unroll
    for (int c = 0; c < 4; ++c) {
      const int flat = c * 1024 + tid * 4;
      const int row = flat >> 7;            // 0..31
      const int col = flat & 127;
      const int grow = n0 + row;
      if (grow < N) {
        float4_t v = *(const float4_t*)&CT[flat];
        const float dv = dinv[grow];
        uint2 pk;
        pk.x = (uint)f2bf(v.x * dv) | ((uint)f2bf(v.y * dv) << 16);
        pk.y = (uint)f2bf(v.z * dv) | ((uint)f2bf(v.w * dv) << 16);
        *(uint2*)(hs + (long)grow * H + col) = pk;
      }
    }
    __syncthreads();
  }
}

// ---------------- aggregation: one wave per node, unrolled gather ----------------
__global__ __launch_bounds__(256) void k_agg(const ushort* __restrict__ hs, const float* __restrict__ dinv,
                                             const int* __restrict__ row_off, const int* __restrict__ csr_src,
                                             const float* __restrict__ b, float* __restrict__ out, int N) {
  const int d = blockIdx.x * 4 + (threadIdx.x >> 6);
  if (d >= N) return;
  const int lane = threadIdx.x & 63;
  const uint* hp = (const uint*)hs;   // 64 uints (=128 bf16) per row

  uint v = hp[(long)d * 64 + lane];   // self message (already * dinv[d])
  float acc0 = bflo(v), acc1 = bfhi(v);

  int j = row_off[d];
  const int end = row_off[d + 1];
  for (; j + 4 <= end; j += 4) {
    const int s0 = csr_src[j], s1 = csr_src[j + 1], s2 = csr_src[j + 2], s3 = csr_src[j + 3];
    const uint v0 = hp[(long)s0 * 64 + lane];
    const uint v1 = hp[(long)s1 * 64 + lane];
    const uint v2 = hp[(long)s2 * 64 + lane];
    const uint v3 = hp[(long)s3 * 64 + lane];
    acc0 += bflo(v0); acc1 += bfhi(v0);
    acc0 += bflo(v1); acc1 += bfhi(v1);
    acc0 += bflo(v2); acc1 += bfhi(v2);
    acc0 += bflo(v3); acc1 += bfhi(v3);
  }
  for (; j < end; ++j) {
    const uint vv = hp[(long)csr_src[j] * 64 + lane];
    acc0 += bflo(vv); acc1 += bfhi(vv);
  }

  const float dd = dinv[d];
  const float2 ob = *(const float2*)(b + lane * 2);
  float2 o;
  o.x = acc0 * dd + ob.x;
  o.y = acc1 * dd + ob.y;
  *(float2*)(out + (long)d * H + lane * 2) = o;
}

extern "C" void kernel_launch(void* const* d_in, const int* in_sizes, int n_in,
                              void* d_out, int out_size, void* d_ws, size_t ws_size,
                              hipStream_t stream) {
  const float* x = (const float*)d_in[0];
  const int*   edge = (const int*)d_in[1];
  const float* W = (const float*)d_in[2];
  const float* b = (const float*)d_in[3];
  float* out = (float*)d_out;

  const int N = in_sizes[0] / H;     // 100000
  const int E = in_sizes[1] / 2;     // 1600000
  const int* src = edge;
  const int* dst = edge + E;
  const int NB = (N + SCAN_BLK - 1) / SCAN_BLK;   // 98

  // workspace layout
  char* w = (char*)d_ws;
  ushort* hs    = (ushort*)w;   w += (size_t)N * H * 2;     // 25.6 MB bf16
  float* dinv   = (float*)w;    w += (size_t)N * 4;
  int*   deg    = (int*)w;      w += (size_t)N * 4;
  int*   row_off= (int*)w;      w += (size_t)(N + 1) * 4;
  int*   cursor = (int*)w;      w += (size_t)N * 4;
  int*   bsum   = (int*)w;      w += (size_t)256 * 4;
  int*   csr    = (int*)w;      w += (size_t)E * 4;
  (void)ws_size;

  hipMemsetAsync(deg, 0, (size_t)N * 4, stream);
  hipMemsetAsync(cursor, 0, (size_t)N * 4, stream);
  k_deg_count<<<(E + 255) / 256, 256, 0, stream>>>(dst, deg, E);
  k_dinv<<<(N + 255) / 256, 256, 0, stream>>>(deg, dinv, N);
  k_scan1<<<NB, 256, 0, stream>>>(deg, row_off, bsum, N);
  k_scan2<<<1, 128, 0, stream>>>(bsum, NB);
  k_scan3<<<NB, 256, 0, stream>>>(row_off, bsum, N, E);
  k_fill<<<(E + 255) / 256, 256, 0, stream>>>(src, dst, row_off, cursor, csr, E);
  k_linear<<<1024, 256, 0, stream>>>(x, W, dinv, hs, N);
  k_agg<<<(N + 3) / 4, 256, 0, stream>>>(hs, dinv, row_off, csr, b, out, N);
}

// Round 4
// 265.835 us; speedup vs baseline: 3.5041x; 1.1456x over previous
//
#include <hip/hip_runtime.h>

#define H 128
#define SCAN_BLK 1024

typedef __attribute__((ext_vector_type(8))) short short8_t;   // 8 bf16
typedef __attribute__((ext_vector_type(4))) float float4_t;

__device__ __forceinline__ ushort f2bf(float f) {
  uint u = __float_as_uint(f);
  u += 0x7fff + ((u >> 16) & 1);          // RNE
  return (ushort)(u >> 16);
}
__device__ __forceinline__ float bflo(uint v) { return __uint_as_float(v << 16); }
__device__ __forceinline__ float bfhi(uint v) { return __uint_as_float(v & 0xffff0000u); }

// ---------------- degree ----------------
__global__ __launch_bounds__(256) void k_deg_count(const int* __restrict__ dst, int* deg, int E) {
  int e = blockIdx.x * 256 + threadIdx.x;
  if (e < E) atomicAdd(&deg[dst[e]], 1);
}

// ---------------- exclusive scan (3-pass), dinv fused into pass 1 ----------------
__global__ __launch_bounds__(256) void k_scan1(const int* __restrict__ in, int* __restrict__ out,
                                               int* __restrict__ bsum, float* __restrict__ dinv, int N) {
  __shared__ int ls[256];
  const int base = blockIdx.x * SCAN_BLK + threadIdx.x * 4;
  int v0 = 0, v1 = 0, v2 = 0, v3 = 0;
  if (base + 3 < N) {
    const int4 q = *(const int4*)(in + base);
    v0 = q.x; v1 = q.y; v2 = q.z; v3 = q.w;
  } else {
    if (base     < N) v0 = in[base];
    if (base + 1 < N) v1 = in[base + 1];
    if (base + 2 < N) v2 = in[base + 2];
    if (base + 3 < N) v3 = in[base + 3];
  }
  // fused dinv = rsqrt(deg + 1 self loop)
  if (base     < N) dinv[base]     = rsqrtf((float)(1 + v0));
  if (base + 1 < N) dinv[base + 1] = rsqrtf((float)(1 + v1));
  if (base + 2 < N) dinv[base + 2] = rsqrtf((float)(1 + v2));
  if (base + 3 < N) dinv[base + 3] = rsqrtf((float)(1 + v3));

  const int t = v0 + v1 + v2 + v3;
  ls[threadIdx.x] = t;
  __syncthreads();
  for (int off = 1; off < 256; off <<= 1) {
    int x = (threadIdx.x >= off) ? ls[threadIdx.x - off] : 0;
    __syncthreads();
    ls[threadIdx.x] += x;
    __syncthreads();
  }
  const int excl = ls[threadIdx.x] - t;
  if (threadIdx.x == 255) bsum[blockIdx.x] = ls[255];
  const int e0 = excl, e1 = e0 + v0, e2 = e1 + v1, e3 = e2 + v2;
  if (base     < N) out[base]     = e0;
  if (base + 1 < N) out[base + 1] = e1;
  if (base + 2 < N) out[base + 2] = e2;
  if (base + 3 < N) out[base + 3] = e3;
}

__global__ __launch_bounds__(128) void k_scan2(int* bsum, int nb) {
  __shared__ int ls[128];
  int t = (threadIdx.x < nb) ? bsum[threadIdx.x] : 0;
  ls[threadIdx.x] = t;
  __syncthreads();
  for (int off = 1; off < 128; off <<= 1) {
    int x = (threadIdx.x >= off) ? ls[threadIdx.x - off] : 0;
    __syncthreads();
    ls[threadIdx.x] += x;
    __syncthreads();
  }
  if (threadIdx.x < nb) bsum[threadIdx.x] = ls[threadIdx.x] - t;  // exclusive
}

__global__ __launch_bounds__(256) void k_scan3(int* out, const int* __restrict__ bsum, int N, int E) {
  const int add = bsum[blockIdx.x];
  const int base = blockIdx.x * SCAN_BLK + threadIdx.x * 4;
  #pragma unroll
  for (int j = 0; j < 4; ++j) {
    int idx = base + j;
    if (idx < N) out[idx] += add;
  }
  if (blockIdx.x == 0 && threadIdx.x == 0) out[N] = E;
}

// ---------------- CSR fill, XCD-pinned by dst region ----------------
// block b: region = b&7 (round-robin -> XCD), chunk = b>>3. Streams its chunk of dst,
// keeps only edges whose dst is in its region -> each region's csr range is written
// by ONE XCD's L2 -> write merging instead of 16x line amplification.
__global__ __launch_bounds__(256) void k_fill2(const int* __restrict__ src, const int* __restrict__ dst,
                                               const int* __restrict__ row_off, int* cursor,
                                               int* __restrict__ csr_src, int E, int npr, int chunks) {
  const int reg   = blockIdx.x & 7;
  const int chunk = blockIdx.x >> 3;
  const int lo = reg * npr;
  const int hi = lo + npr;
  const int e0 = (int)((long)chunk * E / chunks);
  const int e1 = (int)((long)(chunk + 1) * E / chunks);
  for (int e = e0 + threadIdx.x; e < e1; e += 256) {
    const int d = dst[e];
    if (d >= lo && d < hi) {
      const int p = atomicAdd(&cursor[d], 1);
      csr_src[row_off[d] + p] = src[e];
    }
  }
}

// ---------------- linear: hs = (x @ W^T) * dinv[row], stored bf16 ----------------
__global__ __launch_bounds__(256) void k_linear(const float* __restrict__ x, const float* __restrict__ W,
                                                const float* __restrict__ dinv, ushort* __restrict__ hs, int N) {
  __shared__ float CT[32 * 128];
  const int tid  = threadIdx.x;
  const int lane = tid & 63;
  const int wid  = tid >> 6;
  const int rg   = wid >> 1;
  const int cg   = wid & 1;
  const int q    = lane >> 4;
  const int lm   = lane & 15;

  short8_t bfr[4][4];
  #pragma unroll
  for (int kk = 0; kk < 4; ++kk) {
    #pragma unroll
    for (int nf = 0; nf < 4; ++nf) {
      const float* wp = W + (cg * 64 + nf * 16 + lm) * 128 + kk * 32 + q * 8;
      float4_t w0 = *(const float4_t*)wp;
      float4_t w1 = *(const float4_t*)(wp + 4);
      union { short8_t s; ushort u[8]; } t;
      t.u[0] = f2bf(w0.x); t.u[1] = f2bf(w0.y); t.u[2] = f2bf(w0.z); t.u[3] = f2bf(w0.w);
      t.u[4] = f2bf(w1.x); t.u[5] = f2bf(w1.y); t.u[6] = f2bf(w1.z); t.u[7] = f2bf(w1.w);
      bfr[kk][nf] = t.s;
    }
  }

  const int ntiles = (N + 31) / 32;
  for (int tile = blockIdx.x; tile < ntiles; tile += gridDim.x) {
    const int n0 = tile * 32;
    const int arow = n0 + rg * 16 + lm;
    const int arow_c = (arow < N) ? arow : (N - 1);
    const float* xp = x + (long)arow_c * H + q * 8;
    short8_t afr[4];
    #pragma unroll
    for (int kk = 0; kk < 4; ++kk) {
      float4_t x0 = *(const float4_t*)(xp + kk * 32);
      float4_t x1 = *(const float4_t*)(xp + kk * 32 + 4);
      union { short8_t s; ushort u[8]; } t;
      t.u[0] = f2bf(x0.x); t.u[1] = f2bf(x0.y); t.u[2] = f2bf(x0.z); t.u[3] = f2bf(x0.w);
      t.u[4] = f2bf(x1.x); t.u[5] = f2bf(x1.y); t.u[6] = f2bf(x1.z); t.u[7] = f2bf(x1.w);
      afr[kk] = t.s;
    }

    float4_t acc[4];
    #pragma unroll
    for (int nf = 0; nf < 4; ++nf) acc[nf] = (float4_t){0.f, 0.f, 0.f, 0.f};
    #pragma unroll
    for (int kk = 0; kk < 4; ++kk) {
      #pragma unroll
      for (int nf = 0; nf < 4; ++nf)
        acc[nf] = __builtin_amdgcn_mfma_f32_16x16x32_bf16(afr[kk], bfr[kk][nf], acc[nf], 0, 0, 0);
    }

    #pragma unroll
    for (int nf = 0; nf < 4; ++nf) {
      #pragma unroll
      for (int r = 0; r < 4; ++r)
        CT[(rg * 16 + q * 4 + r) * 128 + cg * 64 + nf * 16 + lm] = acc[nf][r];
    }
    __syncthreads();

    #pragma unroll
    for (int c = 0; c < 4; ++c) {
      const int flat = c * 1024 + tid * 4;
      const int row = flat >> 7;
      const int col = flat & 127;
      const int grow = n0 + row;
      if (grow < N) {
        float4_t v = *(const float4_t*)&CT[flat];
        const float dv = dinv[grow];
        uint2 pk;
        pk.x = (uint)f2bf(v.x * dv) | ((uint)f2bf(v.y * dv) << 16);
        pk.y = (uint)f2bf(v.z * dv) | ((uint)f2bf(v.w * dv) << 16);
        *(uint2*)(hs + (long)grow * H + col) = pk;
      }
    }
    __syncthreads();
  }
}

// ---------------- aggregation: one wave per node, 8-deep unrolled gather ----------------
__global__ __launch_bounds__(256) void k_agg(const ushort* __restrict__ hs, const float* __restrict__ dinv,
                                             const int* __restrict__ row_off, const int* __restrict__ csr_src,
                                             const float* __restrict__ b, float* __restrict__ out, int N) {
  const int d = blockIdx.x * 4 + (threadIdx.x >> 6);
  if (d >= N) return;
  const int lane = threadIdx.x & 63;
  const uint* hp = (const uint*)hs;

  uint v = hp[(long)d * 64 + lane];   // self message (already * dinv[d])
  float acc0 = bflo(v), acc1 = bfhi(v);

  int j = row_off[d];
  const int end = row_off[d + 1];
  for (; j + 8 <= end; j += 8) {
    const int s0 = csr_src[j],     s1 = csr_src[j + 1], s2 = csr_src[j + 2], s3 = csr_src[j + 3];
    const int s4 = csr_src[j + 4], s5 = csr_src[j + 5], s6 = csr_src[j + 6], s7 = csr_src[j + 7];
    const uint v0 = hp[(long)s0 * 64 + lane];
    const uint v1 = hp[(long)s1 * 64 + lane];
    const uint v2 = hp[(long)s2 * 64 + lane];
    const uint v3 = hp[(long)s3 * 64 + lane];
    const uint v4 = hp[(long)s4 * 64 + lane];
    const uint v5 = hp[(long)s5 * 64 + lane];
    const uint v6 = hp[(long)s6 * 64 + lane];
    const uint v7 = hp[(long)s7 * 64 + lane];
    acc0 += bflo(v0); acc1 += bfhi(v0);
    acc0 += bflo(v1); acc1 += bfhi(v1);
    acc0 += bflo(v2); acc1 += bfhi(v2);
    acc0 += bflo(v3); acc1 += bfhi(v3);
    acc0 += bflo(v4); acc1 += bfhi(v4);
    acc0 += bflo(v5); acc1 += bfhi(v5);
    acc0 += bflo(v6); acc1 += bfhi(v6);
    acc0 += bflo(v7); acc1 += bfhi(v7);
  }
  for (; j + 2 <= end; j += 2) {
    const uint va = hp[(long)csr_src[j] * 64 + lane];
    const uint vb = hp[(long)csr_src[j + 1] * 64 + lane];
    acc0 += bflo(va); acc1 += bfhi(va);
    acc0 += bflo(vb); acc1 += bfhi(vb);
  }
  if (j < end) {
    const uint vv = hp[(long)csr_src[j] * 64 + lane];
    acc0 += bflo(vv); acc1 += bfhi(vv);
  }

  const float dd = dinv[d];
  const float2 ob = *(const float2*)(b + lane * 2);
  float2 o;
  o.x = acc0 * dd + ob.x;
  o.y = acc1 * dd + ob.y;
  *(float2*)(out + (long)d * H + lane * 2) = o;
}

extern "C" void kernel_launch(void* const* d_in, const int* in_sizes, int n_in,
                              void* d_out, int out_size, void* d_ws, size_t ws_size,
                              hipStream_t stream) {
  const float* x = (const float*)d_in[0];
  const int*   edge = (const int*)d_in[1];
  const float* W = (const float*)d_in[2];
  const float* b = (const float*)d_in[3];
  float* out = (float*)d_out;

  const int N = in_sizes[0] / H;     // 100000
  const int E = in_sizes[1] / 2;     // 1600000
  const int* src = edge;
  const int* dst = edge + E;
  const int NB = (N + SCAN_BLK - 1) / SCAN_BLK;   // 98

  // workspace layout
  char* w = (char*)d_ws;
  ushort* hs    = (ushort*)w;   w += (size_t)N * H * 2;     // 25.6 MB bf16
  float* dinv   = (float*)w;    w += (size_t)N * 4;
  int*   deg    = (int*)w;      w += (size_t)N * 4;
  int*   row_off= (int*)w;      w += (size_t)(N + 1) * 4;
  int*   cursor = (int*)w;      w += (size_t)N * 4;
  int*   bsum   = (int*)w;      w += (size_t)256 * 4;
  int*   csr    = (int*)w;      w += (size_t)E * 4;
  (void)ws_size;

  const int npr    = (N + 7) / 8;        // nodes per region (12500)
  const int chunks = 784;                // edge chunks; grid = 8*chunks

  hipMemsetAsync(deg, 0, (size_t)N * 4, stream);
  hipMemsetAsync(cursor, 0, (size_t)N * 4, stream);
  k_deg_count<<<(E + 255) / 256, 256, 0, stream>>>(dst, deg, E);
  k_scan1<<<NB, 256, 0, stream>>>(deg, row_off, bsum, dinv, N);
  k_scan2<<<1, 128, 0, stream>>>(bsum, NB);
  k_scan3<<<NB, 256, 0, stream>>>(row_off, bsum, N, E);
  k_fill2<<<8 * chunks, 256, 0, stream>>>(src, dst, row_off, cursor, csr, E, npr, chunks);
  k_linear<<<1024, 256, 0, stream>>>(x, W, dinv, hs, N);
  k_agg<<<(N + 3) / 4, 256, 0, stream>>>(hs, dinv, row_off, csr, b, out, N);
}